// Round 1
// 427.190 us; speedup vs baseline: 1.0387x; 1.0387x over previous
//
#include <hip/hip_runtime.h>
#include <cstdint>
#include <cstddef>

#define DI __device__ __forceinline__

typedef __attribute__((ext_vector_type(8))) short short8;
typedef __attribute__((ext_vector_type(4))) float floatx4;

static constexpr int BATCH = 16384;
static constexpr int H = 1024;

DI unsigned short f32_to_bf16_bits(float x) {
  union { float f; unsigned int u; } c; c.f = x;
  unsigned int r = c.u + 0x7fffu + ((c.u >> 16) & 1u);
  return (unsigned short)(r >> 16);
}

// ---------------- K0a: fp32 -> bf16 cast (prev), vectorized ----------------
// 8 floats/thread: 32B load + 16B store per lane (coalescing sweet spot).
__global__ __launch_bounds__(256) void cast_bf16_kernel(const float* __restrict__ in,
                                                        unsigned short* __restrict__ out) {
  const int i = (blockIdx.x * 256 + threadIdx.x) * 8;
  const float4 v0 = *reinterpret_cast<const float4*>(in + i);
  const float4 v1 = *reinterpret_cast<const float4*>(in + i + 4);
  short8 o;
  o[0] = (short)f32_to_bf16_bits(v0.x);
  o[1] = (short)f32_to_bf16_bits(v0.y);
  o[2] = (short)f32_to_bf16_bits(v0.z);
  o[3] = (short)f32_to_bf16_bits(v0.w);
  o[4] = (short)f32_to_bf16_bits(v1.x);
  o[5] = (short)f32_to_bf16_bits(v1.y);
  o[6] = (short)f32_to_bf16_bits(v1.z);
  o[7] = (short)f32_to_bf16_bits(v1.w);
  *reinterpret_cast<short8*>(out + i) = o;
}

// ------------- K0b: transpose + cast both weights in ONE launch ------------
// z==0: WrT[n][k] = Wur[k][H + n]   (reset-gate half of Wur)
// z==1: UT[n][k]  = U[k][n]
__global__ __launch_bounds__(256) void transpose_cast2_kernel(const float* __restrict__ Wur,
                                                              const float* __restrict__ U,
                                                              unsigned short* __restrict__ WrT,
                                                              unsigned short* __restrict__ UT) {
  __shared__ float tile[32][33];
  const float* in;
  unsigned short* out;
  int src_stride, src_col0;
  if (blockIdx.z == 0) {
    in = Wur; out = WrT; src_stride = 2 * H; src_col0 = H;
  } else {
    in = U; out = UT; src_stride = H; src_col0 = 0;
  }
  const int bx = blockIdx.x * 32;  // k (input row)
  const int by = blockIdx.y * 32;  // n (input col)
  const int tx = threadIdx.x;      // 0..31
  const int ty = threadIdx.y;      // 0..7
#pragma unroll
  for (int i = 0; i < 32; i += 8)
    tile[ty + i][tx] = in[(size_t)(bx + ty + i) * src_stride + src_col0 + by + tx];
  __syncthreads();
#pragma unroll
  for (int i = 0; i < 32; i += 8)
    out[(size_t)(by + ty + i) * H + bx + tx] = f32_to_bf16_bits(tile[tx][ty + i]);
}

// ---------------- fused MFMA GEMM: C = A(MxK) @ Bt(NxK)^T ------------------
// EPI 0: reset-gate epilogue -> X bf16.  EPI 1: tanh/mask epilogue -> out f32.
// launch_bounds(256,3): 3 blocks/CU (m97-class occupancy; LDS 32KB*3=96KB ok,
// VGPR cap ~168 >= acc 64 + frags 32 + addressing).
template <int EPI>
__global__ __launch_bounds__(256, 3) void gemm_fused(const unsigned short* __restrict__ A,
                                                     const unsigned short* __restrict__ Bt,
                                                     const float* __restrict__ inp,
                                                     const float* __restrict__ prev,
                                                     const float* __restrict__ mask,
                                                     unsigned short* __restrict__ Xout,
                                                     float* __restrict__ Out) {
  // Tiles: BM=128, BN=128, BK=64. LDS: two 128x64 bf16 tiles (16 KB each).
  __shared__ __align__(16) unsigned short ldsA[128 * 64];
  __shared__ __align__(16) unsigned short ldsB[128 * 64];

  const int tid = threadIdx.x;
  const int lane = tid & 63;
  const int wave = tid >> 6;
  const int wm = wave >> 1;       // wave row quadrant (0..1)
  const int wn = wave & 1;        // wave col quadrant (0..1)
  const int q = lane >> 4;        // quad 0..3
  const int l16 = lane & 15;

  // XCD-chunked bijective swizzle. Grid is (x=8, y=128) = 1024 blocks; hw
  // assigns xcd = linear_id % 8. Give each XCD a CONTIGUOUS chunk of logical
  // ids ordered x-fastest: resident set per XCD ~= 8 A-panels (2MB) + full B
  // (2MB) = 4MB = L2. A is then HBM-fetched ~once instead of 8x.
  const int sid = blockIdx.y * gridDim.x + blockIdx.x;   // hw linear id
  const int nwg = gridDim.x * gridDim.y;                 // 1024
  const int lid = (sid & 7) * (nwg >> 3) + (sid >> 3);   // logical id
  const int bx = lid & 7;                                // N-block (gridDim.x==8)
  const int by = lid >> 3;                               // M-block
  const int blockM = by * 128;
  const int blockN = bx * 128;

  floatx4 acc[4][4] = {};

  for (int kt = 0; kt < H; kt += 64) {
    // ---- stage A,B tiles: 1024 chunks each of 16B; chunk c -> row r=c>>3,
    // phys chunk pc=c&7 holds logical chunk pc^(r&7) (XOR swizzle so the
    // fragment ds_read_b128s spread over all 8 bank groups: 2-way = free).
#pragma unroll
    for (int j = 0; j < 4; ++j) {
      const int c = j * 256 + tid;
      const int r = c >> 3;
      const int gc = (c & 7) ^ (r & 7);
      const int cb = j * 256 + (wave << 6);  // wave-uniform chunk base
      const unsigned short* srcA = A + (size_t)(blockM + r) * H + kt + gc * 8;
      const unsigned short* srcB = Bt + (size_t)(blockN + r) * H + kt + gc * 8;
#if __has_builtin(__builtin_amdgcn_global_load_lds)
      __builtin_amdgcn_global_load_lds(
          (const __attribute__((address_space(1))) unsigned int*)srcA,
          (__attribute__((address_space(3))) unsigned int*)(&ldsA[cb * 8]), 16, 0, 0);
      __builtin_amdgcn_global_load_lds(
          (const __attribute__((address_space(1))) unsigned int*)srcB,
          (__attribute__((address_space(3))) unsigned int*)(&ldsB[cb * 8]), 16, 0, 0);
#else
      *(short8*)&ldsA[c * 8] = *(const short8*)srcA;
      *(short8*)&ldsB[c * 8] = *(const short8*)srcB;
#endif
    }
#if __has_builtin(__builtin_amdgcn_global_load_lds)
    asm volatile("s_waitcnt vmcnt(0)" ::: "memory");
#endif
    __syncthreads();

    // ---- compute: 2 k-steps of 32, 16 MFMAs each
#pragma unroll
    for (int ks = 0; ks < 2; ++ks) {
      short8 af[4], bfr[4];
#pragma unroll
      for (int i = 0; i < 4; ++i) {
        const int r = wm * 64 + i * 16 + l16;
        const int ch = ks * 4 + q;
        af[i] = *(const short8*)&ldsA[(r * 8 + (ch ^ (r & 7))) * 8];
      }
#pragma unroll
      for (int j = 0; j < 4; ++j) {
        const int r = wn * 64 + j * 16 + l16;
        const int ch = ks * 4 + q;
        bfr[j] = *(const short8*)&ldsB[(r * 8 + (ch ^ (r & 7))) * 8];
      }
#pragma unroll
      for (int i = 0; i < 4; ++i)
#pragma unroll
        for (int j = 0; j < 4; ++j)
          acc[i][j] = __builtin_amdgcn_mfma_f32_16x16x32_bf16(af[i], bfr[j], acc[i][j], 0, 0, 0);
    }
    __syncthreads();
  }

  // ---- epilogue. C/D map: col = lane&15, row = quad*4 + reg (verified m89/m91)
#pragma unroll
  for (int i = 0; i < 4; ++i) {
    const int gr0 = blockM + wm * 64 + i * 16 + q * 4;
#pragma unroll
    for (int j = 0; j < 4; ++j) {
      const int gcol = blockN + wn * 64 + j * 16 + l16;
#pragma unroll
      for (int rg = 0; rg < 4; ++rg) {
        const int gr = gr0 + rg;
        const float v = acc[i][j][rg];
        if (EPI == 0) {
          // reset = sigmoid(G + gate_r); X = state_inp * reset
          const float z = v + inp[(size_t)gr * (3 * H) + 2 * H + gcol];
          const float rst = 1.0f / (1.0f + __expf(-z));
          const float x = inp[(size_t)gr * (3 * H) + gcol] * rst;
          Xout[(size_t)gr * H + gcol] = f32_to_bf16_bits(x);
        } else {
          // out = mask*(tanh(P + s) + 1) + prev   [update cancels; expanded mask form]
          const float s = inp[(size_t)gr * (3 * H) + gcol];
          const float a = v + s;
          const float ns = 1.0f - 2.0f / (__expf(2.0f * a) + 1.0f);  // tanh, overflow-safe
          const float m = mask[gr];
          Out[(size_t)gr * H + gcol] = m * (ns + 1.0f) + prev[(size_t)gr * H + gcol];
        }
      }
    }
  }
}

extern "C" void kernel_launch(void* const* d_in, const int* in_sizes, int n_in,
                              void* d_out, int out_size, void* d_ws, size_t ws_size,
                              hipStream_t stream) {
  const float* inp = (const float*)d_in[0];    // (B, 3H)
  const float* prev = (const float*)d_in[1];   // (B, H)
  const float* mask = (const float*)d_in[2];   // (B,)
  const float* Wur = (const float*)d_in[3];    // (H, 2H)
  const float* U = (const float*)d_in[4];      // (H, H)
  float* out = (float*)d_out;

  // workspace layout
  char* ws = (char*)d_ws;
  unsigned short* prevb = (unsigned short*)ws;                          // B*H bf16 (32 MB)
  unsigned short* Xb = (unsigned short*)(ws + (size_t)BATCH * H * 2);   // B*H bf16 (32 MB)
  unsigned short* WrT = (unsigned short*)(ws + (size_t)BATCH * H * 4);  // H*H bf16 (2 MB)
  unsigned short* UT = WrT + (size_t)H * H;                             // H*H bf16 (2 MB)

  // K0: casts / transposes
  cast_bf16_kernel<<<(BATCH * H) / (256 * 8), 256, 0, stream>>>(prev, prevb);
  transpose_cast2_kernel<<<dim3(H / 32, H / 32, 2), dim3(32, 8), 0, stream>>>(Wur, U, WrT, UT);

  // K1: G = prev@Wr -> reset -> X (bf16)
  gemm_fused<0><<<dim3(H / 128, BATCH / 128), 256, 0, stream>>>(prevb, WrT, inp, nullptr,
                                                                nullptr, Xb, nullptr);
  // K2: P = X@U -> out
  gemm_fused<1><<<dim3(H / 128, BATCH / 128), 256, 0, stream>>>(Xb, UT, inp, prev, mask,
                                                                nullptr, out);
}

// Round 2
// 422.269 us; speedup vs baseline: 1.0508x; 1.0117x over previous
//
#include <hip/hip_runtime.h>
#include <cstdint>
#include <cstddef>

#define DI __device__ __forceinline__

typedef __attribute__((ext_vector_type(8))) short short8;
typedef __attribute__((ext_vector_type(4))) float floatx4;

static constexpr int BATCH = 16384;
static constexpr int H = 1024;
static constexpr int NT = H / 64;       // K-tiles of 64
static constexpr int HALF = 128 * 64;   // ushorts per half-tile (16 KB)

DI unsigned short f32_to_bf16_bits(float x) {
  union { float f; unsigned int u; } c; c.f = x;
  unsigned int r = c.u + 0x7fffu + ((c.u >> 16) & 1u);
  return (unsigned short)(r >> 16);
}

// ---------------- K0a: fp32 -> bf16 cast (prev), vectorized ----------------
__global__ __launch_bounds__(256) void cast_bf16_kernel(const float* __restrict__ in,
                                                        unsigned short* __restrict__ out) {
  const int i = (blockIdx.x * 256 + threadIdx.x) * 8;
  const float4 v0 = *reinterpret_cast<const float4*>(in + i);
  const float4 v1 = *reinterpret_cast<const float4*>(in + i + 4);
  short8 o;
  o[0] = (short)f32_to_bf16_bits(v0.x);
  o[1] = (short)f32_to_bf16_bits(v0.y);
  o[2] = (short)f32_to_bf16_bits(v0.z);
  o[3] = (short)f32_to_bf16_bits(v0.w);
  o[4] = (short)f32_to_bf16_bits(v1.x);
  o[5] = (short)f32_to_bf16_bits(v1.y);
  o[6] = (short)f32_to_bf16_bits(v1.z);
  o[7] = (short)f32_to_bf16_bits(v1.w);
  *reinterpret_cast<short8*>(out + i) = o;
}

// ------------- K0b: transpose + cast both weights in ONE launch ------------
__global__ __launch_bounds__(256) void transpose_cast2_kernel(const float* __restrict__ Wur,
                                                              const float* __restrict__ U,
                                                              unsigned short* __restrict__ WrT,
                                                              unsigned short* __restrict__ UT) {
  __shared__ float tile[32][33];
  const float* in;
  unsigned short* out;
  int src_stride, src_col0;
  if (blockIdx.z == 0) {
    in = Wur; out = WrT; src_stride = 2 * H; src_col0 = H;
  } else {
    in = U; out = UT; src_stride = H; src_col0 = 0;
  }
  const int bx = blockIdx.x * 32;
  const int by = blockIdx.y * 32;
  const int tx = threadIdx.x;
  const int ty = threadIdx.y;
#pragma unroll
  for (int i = 0; i < 32; i += 8)
    tile[ty + i][tx] = in[(size_t)(bx + ty + i) * src_stride + src_col0 + by + tx];
  __syncthreads();
#pragma unroll
  for (int i = 0; i < 32; i += 8)
    out[(size_t)(by + ty + i) * H + bx + tx] = f32_to_bf16_bits(tile[tx][ty + i]);
}

// ------------------- fragment loaders (XOR chunk swizzle) ------------------
// LDS half-tile layout: [row 0..127][8 chunks of 16B]; phys chunk pc holds
// logical chunk pc ^ (row & 7).  16 lanes (l16) at fixed logical chunk ->
// 8 distinct phys chunks -> 2-way bank aliasing = free (m136).
DI void ld8(short8* fr, const unsigned short* base, int wofs, int l16, int q) {
  const int x7 = l16 & 7;
#pragma unroll
  for (int f = 0; f < 4; ++f) {
    const int lr = 32 * f + wofs + l16;
#pragma unroll
    for (int ks = 0; ks < 2; ++ks)
      fr[f * 2 + ks] = *(const short8*)&base[lr * 64 + (((ks * 4 + q) ^ x7) * 8)];
  }
}
DI void ld4(short8* fr, const unsigned short* base, int wofs, int l16, int q) {
  const int x7 = l16 & 7;
#pragma unroll
  for (int jj = 0; jj < 2; ++jj) {
    const int lc = 64 * jj + wofs + l16;
#pragma unroll
    for (int ks = 0; ks < 2; ++ks)
      fr[jj * 2 + ks] = *(const short8*)&base[lc * 64 + (((ks * 4 + q) ^ x7) * 8)];
  }
}

template <int IO, int JO>
DI void mma16(floatx4 (&acc)[8][4], const short8* af, const short8* bf) {
#pragma unroll
  for (int ks = 0; ks < 2; ++ks)
#pragma unroll
    for (int f = 0; f < 4; ++f)
#pragma unroll
      for (int jj = 0; jj < 2; ++jj)
        acc[IO + f][JO + jj] = __builtin_amdgcn_mfma_f32_16x16x32_bf16(
            af[f * 2 + ks], bf[jj * 2 + ks], acc[IO + f][JO + jj], 0, 0, 0);
}

// ---------------- 256x256 8-wave 4-phase pipelined GEMM --------------------
// C = A(MxK) @ Bt(NxK)^T.  EPI 0: reset epilogue -> X bf16.  EPI 1: tanh/mask.
// Schedule: per K-tile, 4 phases (C-quadrants Mh,Nh). Per phase: ds_read
// fragments | stage ONE half-tile of tile t+1 | s_barrier | MFMA x16 (setprio)
// | counted vmcnt | s_barrier.  vmcnt never drains to 0 in the loop (T4).
// Raw s_barrier (NOT __syncthreads) keeps prefetch loads in flight.
template <int EPI>
__global__ __launch_bounds__(512, 2) void gemm_fused(const unsigned short* __restrict__ A,
                                                     const unsigned short* __restrict__ Bt,
                                                     const float* __restrict__ inp,
                                                     const float* __restrict__ prev,
                                                     const float* __restrict__ mask,
                                                     unsigned short* __restrict__ Xout,
                                                     float* __restrict__ Out) {
  // [buf 0/1][half 0/1][128][64] bf16 for A and B: 64 KB + 64 KB = 128 KB.
  __shared__ __align__(16) unsigned short ldsA[2 * 2 * HALF];
  __shared__ __align__(16) unsigned short ldsB[2 * 2 * HALF];

  const int tid = threadIdx.x;
  const int lane = tid & 63;
  const int w = tid >> 6;        // wave 0..7
  const int wm16 = (w >> 2) * 16;  // 2 M-wave rows
  const int wn16 = (w & 3) * 16;   // 4 N-wave cols
  const int q = lane >> 4;
  const int l16 = lane & 15;

  // XCD-chunked bijective swizzle: 256 blocks, 8 XCDs, 32 contiguous each.
  const int sid = blockIdx.y * gridDim.x + blockIdx.x;
  const int lid = (sid & 7) * 32 + (sid >> 3);
  const int blockN = (lid & 3) * 256;   // gridDim.x == 4
  const int blockM = (lid >> 2) * 256;

  // staging constants: load n covers chunk c = n*512 + tid of a half-tile.
  // phys chunk pc = c&7 sources logical chunk pc ^ (r&7)  (inverse == same XOR).
  int srcoff[2], dstch[2];
#pragma unroll
  for (int n = 0; n < 2; ++n) {
    const int c = n * 512 + tid;
    const int r = c >> 3;
    const int gc = (c & 7) ^ (r & 7);
    srcoff[n] = r * H + gc * 8;       // ushort offset from (tile-half, kt) base
    dstch[n] = n * 512 + w * 64;      // wave-uniform chunk base (lane adds 16B)
  }

  const unsigned short* Ab = A + (size_t)blockM * H;
  const unsigned short* Bb = Bt + (size_t)blockN * H;

  auto stage = [&](const unsigned short* gsrc, unsigned short* ldst) {
#pragma unroll
    for (int n = 0; n < 2; ++n) {
      __builtin_amdgcn_global_load_lds(
          (const __attribute__((address_space(1))) unsigned int*)(gsrc + srcoff[n]),
          (__attribute__((address_space(3))) unsigned int*)(ldst + dstch[n] * 8), 16, 0, 0);
    }
  };

  floatx4 acc[8][4] = {};
  short8 af[8], bf0[4], bf1[4];

  // ---- prologue: stage tile 0 (order = first-use order: A0, B0, B1, A1)
  stage(Ab, ldsA);
  stage(Bb, ldsB);
  stage(Bb + 128 * H, ldsB + HALF);
  stage(Ab + 128 * H, ldsA + HALF);
  asm volatile("s_waitcnt vmcnt(4)" ::: "memory");  // A0,B0 landed; B1,A1 in flight
  __builtin_amdgcn_s_barrier();

  for (int t = 0; t < NT; ++t) {
    const int cur = t & 1;
    const int kn = ((t + 1) & (NT - 1)) * 64;  // wrap: last iter re-stages tile 0 (unused)
    const unsigned short* lAc = ldsA + cur * 2 * HALF;
    const unsigned short* lBc = ldsB + cur * 2 * HALF;
    unsigned short* lAn = ldsA + (cur ^ 1) * 2 * HALF;
    unsigned short* lBn = ldsB + (cur ^ 1) * 2 * HALF;

    // ---- P1: quadrant (Mh0, Nh0); stage A0(t+1)
    ld8(af, lAc, wm16, l16, q);
    ld4(bf0, lBc, wn16, l16, q);
    stage(Ab + kn, lAn);
    __builtin_amdgcn_s_barrier();
    __builtin_amdgcn_s_setprio(1);
    mma16<0, 0>(acc, af, bf0);
    __builtin_amdgcn_s_setprio(0);
    asm volatile("s_waitcnt vmcnt(4)" ::: "memory");  // B1(t) done (needed P2)
    __builtin_amdgcn_s_barrier();

    // ---- P2: (Mh0, Nh1) reuse af; stage B0(t+1)
    ld4(bf1, lBc + HALF, wn16, l16, q);
    stage(Bb + kn, lBn);
    __builtin_amdgcn_s_barrier();
    __builtin_amdgcn_s_setprio(1);
    mma16<0, 2>(acc, af, bf1);
    __builtin_amdgcn_s_setprio(0);
    asm volatile("s_waitcnt vmcnt(4)" ::: "memory");  // A1(t) done (needed P3)
    __builtin_amdgcn_s_barrier();

    // ---- P3: (Mh1, Nh1) reuse bf1; stage B1(t+1)
    ld8(af, lAc + HALF, wm16, l16, q);
    stage(Bb + 128 * H + kn, lBn + HALF);
    __builtin_amdgcn_s_barrier();
    __builtin_amdgcn_s_setprio(1);
    mma16<4, 2>(acc, af, bf1);
    __builtin_amdgcn_s_setprio(0);
    __builtin_amdgcn_s_barrier();  // no vmcnt: P4 reads nothing new from LDS

    // ---- P4: (Mh1, Nh0) reuse af, bf0; stage A1(t+1)
    stage(Ab + 128 * H + kn, lAn + HALF);
    __builtin_amdgcn_s_barrier();
    __builtin_amdgcn_s_setprio(1);
    mma16<4, 0>(acc, af, bf0);
    __builtin_amdgcn_s_setprio(0);
    asm volatile("s_waitcnt vmcnt(4)" ::: "memory");  // A0,B0(t+1) done (needed next P1)
    __builtin_amdgcn_s_barrier();
  }

  // ---- epilogue. C/D map per frag: col = l16, row = q*4 + rg (verified m89/m91).
  // Frag (i,j): row base = 128*(i>>2) + 32*(i&3) + wm16; col = 128*(j>>1) + 64*(j&1) + wn16.
#pragma unroll
  for (int i = 0; i < 8; ++i) {
    const int gr0 = blockM + 128 * (i >> 2) + 32 * (i & 3) + wm16 + q * 4;
#pragma unroll
    for (int j = 0; j < 4; ++j) {
      const int gcol = blockN + 128 * (j >> 1) + 64 * (j & 1) + wn16 + l16;
#pragma unroll
      for (int rg = 0; rg < 4; ++rg) {
        const int gr = gr0 + rg;
        const float v = acc[i][j][rg];
        if (EPI == 0) {
          // reset = sigmoid(G + gate_r); X = state_inp * reset
          const float z = v + inp[(size_t)gr * (3 * H) + 2 * H + gcol];
          const float rst = 1.0f / (1.0f + __expf(-z));
          const float x = inp[(size_t)gr * (3 * H) + gcol] * rst;
          Xout[(size_t)gr * H + gcol] = f32_to_bf16_bits(x);
        } else {
          // out = mask*(tanh(P + s) + 1) + prev   [update cancels]
          const float s = inp[(size_t)gr * (3 * H) + gcol];
          const float a = v + s;
          const float ns = 1.0f - 2.0f / (__expf(2.0f * a) + 1.0f);
          const float m = mask[gr];
          Out[(size_t)gr * H + gcol] = m * (ns + 1.0f) + prev[(size_t)gr * H + gcol];
        }
      }
    }
  }
}

extern "C" void kernel_launch(void* const* d_in, const int* in_sizes, int n_in,
                              void* d_out, int out_size, void* d_ws, size_t ws_size,
                              hipStream_t stream) {
  const float* inp = (const float*)d_in[0];    // (B, 3H)
  const float* prev = (const float*)d_in[1];   // (B, H)
  const float* mask = (const float*)d_in[2];   // (B,)
  const float* Wur = (const float*)d_in[3];    // (H, 2H)
  const float* U = (const float*)d_in[4];      // (H, H)
  float* out = (float*)d_out;

  char* ws = (char*)d_ws;
  unsigned short* prevb = (unsigned short*)ws;                          // B*H bf16
  unsigned short* Xb = (unsigned short*)(ws + (size_t)BATCH * H * 2);   // B*H bf16
  unsigned short* WrT = (unsigned short*)(ws + (size_t)BATCH * H * 4);  // H*H bf16
  unsigned short* UT = WrT + (size_t)H * H;                             // H*H bf16

  cast_bf16_kernel<<<(BATCH * H) / (256 * 8), 256, 0, stream>>>(prev, prevb);
  transpose_cast2_kernel<<<dim3(H / 32, H / 32, 2), dim3(32, 8), 0, stream>>>(Wur, U, WrT, UT);

  // K1: G = prev@Wr -> reset -> X (bf16).  grid 4x64 = 256 blocks = 1/CU.
  gemm_fused<0><<<dim3(H / 256, BATCH / 256), 512, 0, stream>>>(prevb, WrT, inp, nullptr,
                                                                nullptr, Xb, nullptr);
  // K2: P = X@U -> out
  gemm_fused<1><<<dim3(H / 256, BATCH / 256), 512, 0, stream>>>(Xb, UT, inp, prev, mask,
                                                                nullptr, out);
}